// Round 4
// baseline (233.418 us; speedup 1.0000x reference)
//
#include <hip/hip_runtime.h>

// MomentumLIF: x[N,T,D] f32 -> spikes[N,T,D] f32 (0/1)
//   v_t = mom*v + x_t - lamb*u ; u_t = 0.5*u + v_t ; s = (u>=1); u *= (1-s)
// Sequential over T (recurrence), parallel over N*D chains.
//
// R4: R1-R3 all hit the same ~80us / 2.5 TB/s wall regardless of structure.
// Mechanism: per-iteration load->consume->store forces s_waitcnt vmcnt(0)
// (stores share vmcnt; in-order retire), exposing a full memory round trip
// per iteration (MLP=1). Fix: phase-batched chunks of CH=16 timesteps with
// double buffering -- issue chunk c+1's 16 loads BEFORE computing chunk c,
// so the pre-compute wait is vmcnt(16) and stores retire under older loads.
// MLP per wave = 16; ~64KB outstanding per CU.

#define N_ 64
#define T_ 64
#define D_ 8192
#define CH 16                 // timesteps per chunk
#define NC (T_ / CH)          // 4 chunks

__global__ __launch_bounds__(256) void MomentumLIF_kernel(
    const float* __restrict__ x,
    const float* __restrict__ momp,
    const float* __restrict__ lambp,
    float* __restrict__ out)
{
    // Match numpy f32 semantics exactly: no FMA contraction anywhere in here.
#pragma clang fp contract(off)
    const float mom  = momp[0];
    const float lamb = lambp[0];
    const float decay = 0.5f;   // 1 - 1/TAU, exact

    const int tid = blockIdx.x * blockDim.x + threadIdx.x;  // [0, N*D)
    const int n = tid >> 13;         // / D_
    const int d = tid & (D_ - 1);

    const float* __restrict__ xp = x   + (size_t)n * T_ * D_ + d;
    float*       __restrict__ op = out + (size_t)n * T_ * D_ + d;

    float u = 0.f, v = 0.f;
    float xb[2][CH];            // double-buffered x chunk (registers)

    // Preload chunk 0.
#pragma unroll
    for (int i = 0; i < CH; ++i)
        xb[0][i] = xp[(size_t)i * D_];

#pragma unroll
    for (int c = 0; c < NC; ++c) {
        const int cur = c & 1;
        const int nxt = (c + 1) & 1;

        // Issue next chunk's loads BEFORE consuming current chunk, so the
        // wait before compute is vmcnt(CH), not vmcnt(0).
        if (c + 1 < NC) {
#pragma unroll
            for (int i = 0; i < CH; ++i)
                xb[nxt][i] = xp[(size_t)((c + 1) * CH + i) * D_];
        }

        // Compute 16 spikes into a register buffer (no memory ops in here).
        float sb[CH];
#pragma unroll
        for (int i = 0; i < CH; ++i) {
            const float xt = xb[cur][i];
            float t1 = mom * v;        // separately rounded, matches numpy
            float t2 = lamb * u;
            v = (t1 + xt) - t2;
            u = decay * u + v;
            const bool sp = (u >= 1.0f);
            sb[i] = sp ? 1.0f : 0.0f;
            u = sp ? 0.0f : u;         // u*(1-s) is exactly this select
        }

        // Batch store; these retire under the next chunk's older loads.
#pragma unroll
        for (int i = 0; i < CH; ++i)
            __builtin_nontemporal_store(sb[i], op + (size_t)(c * CH + i) * D_);
    }
}

extern "C" void kernel_launch(void* const* d_in, const int* in_sizes, int n_in,
                              void* d_out, int out_size, void* d_ws, size_t ws_size,
                              hipStream_t stream) {
    const float* x    = (const float*)d_in[0];
    const float* momp = (const float*)d_in[1];
    const float* lamb = (const float*)d_in[2];
    float* out = (float*)d_out;

    const int threads = N_ * D_;         // 524288 chains, 1 per thread
    dim3 block(256);
    dim3 grid(threads / 256);            // 2048 blocks -> 8 blocks/CU
    hipLaunchKernelGGL(MomentumLIF_kernel, grid, block, 0, stream,
                       x, momp, lamb, out);
}